// Round 6
// baseline (344.932 us; speedup 1.0000x reference)
//
#include <hip/hip_runtime.h>
#include <math.h>

// Swin block, single fused bf16-MFMA kernel (per-window), LDS-aliased phases.
// B=64, H=W=56, C=96, WS=7, SS=3, NH=3, HD=32, N=49 (padded 64), nW=64.

#define CDIM 96
#define SCALE_QK 0.17677669529663687f  // 32^-0.5
#define NW 8                            // waves per block

typedef __attribute__((ext_vector_type(8))) short bf16x8;
typedef __attribute__((ext_vector_type(4))) float f32x4;
typedef __attribute__((ext_vector_type(2))) unsigned int u32x2;

__device__ inline unsigned short f2b(float f) {
    union { float f; unsigned u; } v; v.f = f;
    unsigned r = v.u + 0x7FFF + ((v.u >> 16) & 1);   // RNE
    return (unsigned short)(r >> 16);
}
__device__ inline unsigned pk2(float a, float b) {
    return (unsigned)f2b(a) | ((unsigned)f2b(b) << 16);
}
__device__ inline float bitsf(unsigned u) {
    union { unsigned u; float f; } v; v.u = u; return v.f;
}

// ---------------- Kernel 0a: weights fp32 -> bf16 ----------------
// ws shorts: qkv_w [288*96] @0, proj_w @27648, fc1_w @36864, fc2_w @73728 (end 110592),
// bm_frag bf16 @110592 (786432 shorts).
__global__ __launch_bounds__(256) void conv_w_kernel(
    const float* __restrict__ qkv_w, const float* __restrict__ proj_w,
    const float* __restrict__ fc1_w, const float* __restrict__ fc2_w,
    unsigned short* __restrict__ ws)
{
    const int i = blockIdx.x * 256 + threadIdx.x;
    if (i < 27648)       ws[i] = f2b(qkv_w[i]);
    else if (i < 36864)  ws[i] = f2b(proj_w[i - 27648]);
    else if (i < 73728)  ws[i] = f2b(fc1_w[i - 36864]);
    else if (i < 110592) ws[i] = f2b(fc2_w[i - 73728]);
}

// ---------------- Kernel 0b: bias+mask in MFMA C-fragment layout, bf16 ----------------
// bmf[(((widx*3+h)*4 + kt)*4 + mt)*64 + lane] -> 4 bf16 (rr = 0..3).
// S'[k][q]: col(lane&15)=q-local, row=(lane>>4)*4+rr = k-local.
__global__ __launch_bounds__(256) void build_bmfrag_kernel(
    const float* __restrict__ attn_mask, const float* __restrict__ rel_bias_table,
    const int* __restrict__ rel_index, unsigned short* __restrict__ bmf)
{
    const int i = blockIdx.x * 256 + threadIdx.x;   // 196608 total
    const int lane = i & 63;
    const int mt = (i >> 6) & 3;
    const int kt = (i >> 8) & 3;
    const int t3 = i >> 10;                          // widx*3 + h
    const int h = t3 % 3, widx = t3 / 3;
    const int q = mt * 16 + (lane & 15);
    const int kb = kt * 16 + (lane >> 4) * 4;
    float vv[4];
    #pragma unroll
    for (int rr = 0; rr < 4; ++rr) {
        const int k = kb + rr;
        float val = -1.0e30f;
        if (q < 49 && k < 49) {
            const int idx = q * 49 + k;
            val = rel_bias_table[rel_index[idx] * 3 + h] + attn_mask[widx * 2401 + idx];
        }
        vv[rr] = val;
    }
    u32x2 pw;
    pw.x = pk2(vv[0], vv[1]);
    pw.y = pk2(vv[2], vv[3]);
    *(u32x2*)(bmf + (size_t)i * 4) = pw;
}

// ---------------- Fused kernel: LN1+shift+attn+proj -> h(LDS) -> LN2+MLP -> out ----------------
// LDS layout (bytes), 72192 total:
//   xt  [64][104] u16  @0        (LN1 out; attn-out after ph3; LN2 out "xs" after ph4)
//   qs  [64][104] u16  @13312 \  aliased by hbuf [64][100] f32 @13312 (after ph3)
//   kss [64][104] u16  @26624 /
//   vs  [96][72]  u16  @39936 \  aliased by m1 [64][200] u16 @39936 (after ph3)
//   ps  [8][16][72]u16 @53760 /
__global__ __launch_bounds__(512, 4) void swin_fused(
    const float* __restrict__ x,
    const float* __restrict__ ln1_g, const float* __restrict__ ln1_b,
    const float* __restrict__ qkv_b, const float* __restrict__ proj_b,
    const float* __restrict__ ln2_g, const float* __restrict__ ln2_b,
    const float* __restrict__ fc1_b, const float* __restrict__ fc2_b,
    const unsigned short* __restrict__ wqkv,   // [288][96] bf16
    const unsigned short* __restrict__ wproj,  // [96][96] bf16
    const unsigned short* __restrict__ wfc1,   // [384][96] bf16
    const unsigned short* __restrict__ wfc2,   // [96][384] bf16
    const unsigned short* __restrict__ bmfrag, // fragment-layout bias+mask, bf16
    float* __restrict__ out)
{
    __shared__ __align__(16) unsigned char smem[72192];
    unsigned short (*xt)[104]    = (unsigned short(*)[104])(smem);
    unsigned short (*qs)[104]    = (unsigned short(*)[104])(smem + 13312);
    unsigned short (*kss)[104]   = (unsigned short(*)[104])(smem + 26624);
    unsigned short (*vs)[72]     = (unsigned short(*)[72])(smem + 39936);
    unsigned short (*ps)[16][72] = (unsigned short(*)[16][72])(smem + 53760);
    float          (*hbuf)[100]  = (float(*)[100])(smem + 13312);
    unsigned short (*m1)[200]    = (unsigned short(*)[200])(smem + 39936);
    unsigned short (*xs)[104]    = xt;

    const int w = blockIdx.x, b = w >> 6, widx = w & 63;
    const int wi = widx >> 3, wj = widx & 7;
    const int tid = threadIdx.x, wave = tid >> 6, lane = tid & 63;
    const int l15 = lane & 15, lk = (lane >> 4) * 8, g4 = (lane >> 4) * 4;

    // ---- Phase 1: LN1 + shifted gather (roll -3,-3); 8 threads per row ----
    {
        const int n = tid >> 3, oc = tid & 7;
        if (n < 49) {
            const int p = n / 7, qq = n - 7 * p;
            int sr = wi * 7 + p + 3;   if (sr >= 56) sr -= 56;
            int scl = wj * 7 + qq + 3; if (scl >= 56) scl -= 56;
            const float* xr = x + ((size_t)b * 3136 + (size_t)(sr * 56 + scl)) * CDIM + oc * 12;
            float vals[12];
            float s = 0.f, ss2 = 0.f;
            #pragma unroll
            for (int i = 0; i < 3; ++i) {
                const float4 f = *(const float4*)(xr + i * 4);
                vals[i*4+0] = f.x; vals[i*4+1] = f.y; vals[i*4+2] = f.z; vals[i*4+3] = f.w;
                s += f.x + f.y + f.z + f.w;
                ss2 += f.x*f.x + f.y*f.y + f.z*f.z + f.w*f.w;
            }
            s += __shfl_xor(s, 1);  ss2 += __shfl_xor(ss2, 1);
            s += __shfl_xor(s, 2);  ss2 += __shfl_xor(ss2, 2);
            s += __shfl_xor(s, 4);  ss2 += __shfl_xor(ss2, 4);
            const float mean = s * (1.f / 96.f);
            const float rstd = rsqrtf(ss2 * (1.f / 96.f) - mean * mean + 1e-5f);
            #pragma unroll
            for (int v4 = 0; v4 < 3; ++v4) {
                const float4 gg = *(const float4*)(ln1_g + oc * 12 + v4 * 4);
                const float4 bb = *(const float4*)(ln1_b + oc * 12 + v4 * 4);
                u32x2 pv;
                pv.x = pk2((vals[v4*4+0]-mean)*rstd*gg.x + bb.x,
                           (vals[v4*4+1]-mean)*rstd*gg.y + bb.y);
                pv.y = pk2((vals[v4*4+2]-mean)*rstd*gg.z + bb.z,
                           (vals[v4*4+3]-mean)*rstd*gg.w + bb.w);
                *(u32x2*)&xt[n][oc * 12 + v4 * 4] = pv;
            }
        } else {
            const u32x2 z = {0u, 0u};
            #pragma unroll
            for (int v4 = 0; v4 < 3; ++v4) *(u32x2*)&xt[n][oc * 12 + v4 * 4] = z;
        }
    }
    __syncthreads();

    // ---- Phase 2: qkv projection, static 9 iters/wave, packed 8B stores ----
    #pragma unroll
    for (int i = 0; i < 9; ++i) {
        const int t = wave + 8 * i;
        if (t < 48) {
            const int qt = t >> 2, ntt = t & 3;
            f32x4 acc = {0.f, 0.f, 0.f, 0.f};
            #pragma unroll
            for (int ksp = 0; ksp < 3; ++ksp) {
                const bf16x8 a = *(const bf16x8*)(wqkv + (size_t)(qt * 16 + l15) * 96 + ksp * 32 + lk);
                const bf16x8 bx = *(const bf16x8*)&xt[ntt * 16 + l15][ksp * 32 + lk];
                acc = __builtin_amdgcn_mfma_f32_16x16x32_bf16(a, bx, acc, 0, 0, 0);
            }
            const int f0 = qt * 16 + g4;
            const float4 bias = *(const float4*)(qkv_b + f0);
            const int tok = ntt * 16 + l15;
            u32x2 pw;
            if (qt < 6) {                            // Q (scale folded)
                pw.x = pk2((acc[0] + bias.x) * SCALE_QK, (acc[1] + bias.y) * SCALE_QK);
                pw.y = pk2((acc[2] + bias.z) * SCALE_QK, (acc[3] + bias.w) * SCALE_QK);
                *(u32x2*)&qs[tok][f0] = pw;
            } else {                                 // K
                pw.x = pk2(acc[0] + bias.x, acc[1] + bias.y);
                pw.y = pk2(acc[2] + bias.z, acc[3] + bias.w);
                *(u32x2*)&kss[tok][f0 - 96] = pw;
            }
        } else {
            const int u = t - 48, mtt = u / 6, vt = u - 6 * mtt;
            f32x4 acc = {0.f, 0.f, 0.f, 0.f};
            #pragma unroll
            for (int ksp = 0; ksp < 3; ++ksp) {
                const bf16x8 a = *(const bf16x8*)&xt[mtt * 16 + l15][ksp * 32 + lk];
                const bf16x8 bw = *(const bf16x8*)(wqkv + (size_t)(192 + vt * 16 + l15) * 96 + ksp * 32 + lk);
                acc = __builtin_amdgcn_mfma_f32_16x16x32_bf16(a, bw, acc, 0, 0, 0);
            }
            const float bias = qkv_b[192 + vt * 16 + l15];
            u32x2 pw;
            pw.x = pk2(acc[0] + bias, acc[1] + bias);
            pw.y = pk2(acc[2] + bias, acc[3] + bias);
            *(u32x2*)&vs[vt * 16 + l15][mtt * 16 + g4] = pw;
        }
    }
    __syncthreads();

    // ---- Phase 3 (no barriers): unit=(h,mt); swapped QK^T, register softmax, swapped PV ----
    #pragma unroll
    for (int it = 0; it < 2; ++it) {
        const int ui = wave + 8 * it;
        if (ui < 12) {
            const int h = ui >> 2, mt = ui & 3;
            const bf16x8 bq = *(const bf16x8*)&qs[mt * 16 + l15][h * 32 + lk];
            const unsigned short* bmb = bmfrag + ((((size_t)widx * 3 + h) * 4) * 4 + mt) * 64 * 4;
            f32x4 s[4];
            #pragma unroll
            for (int kt = 0; kt < 4; ++kt) {
                const bf16x8 ak = *(const bf16x8*)&kss[kt * 16 + l15][h * 32 + lk];
                const u32x2 cw = *(const u32x2*)(bmb + ((size_t)kt * 4 * 64 + lane) * 4);
                f32x4 c;
                c[0] = bitsf(cw.x << 16); c[1] = bitsf(cw.x & 0xffff0000u);
                c[2] = bitsf(cw.y << 16); c[3] = bitsf(cw.y & 0xffff0000u);
                s[kt] = __builtin_amdgcn_mfma_f32_16x16x32_bf16(ak, bq, c, 0, 0, 0);
            }
            float mx = s[0][0];
            #pragma unroll
            for (int kt = 0; kt < 4; ++kt)
                #pragma unroll
                for (int rr = 0; rr < 4; ++rr) mx = fmaxf(mx, s[kt][rr]);
            mx = fmaxf(mx, __shfl_xor(mx, 16));
            mx = fmaxf(mx, __shfl_xor(mx, 32));
            float sum = 0.f;
            #pragma unroll
            for (int kt = 0; kt < 4; ++kt)
                #pragma unroll
                for (int rr = 0; rr < 4; ++rr) {
                    const float e = __expf(s[kt][rr] - mx);
                    s[kt][rr] = e; sum += e;
                }
            sum += __shfl_xor(sum, 16);
            sum += __shfl_xor(sum, 32);
            const float inv = 1.0f / sum;
            #pragma unroll
            for (int kt = 0; kt < 4; ++kt) {
                u32x2 pw;
                pw.x = pk2(s[kt][0] * inv, s[kt][1] * inv);
                pw.y = pk2(s[kt][2] * inv, s[kt][3] * inv);
                *(u32x2*)&ps[wave][l15][kt * 16 + g4] = pw;
            }
            #pragma unroll
            for (int dt = 0; dt < 2; ++dt) {
                f32x4 o = {0.f, 0.f, 0.f, 0.f};
                #pragma unroll
                for (int c2 = 0; c2 < 2; ++c2) {
                    const bf16x8 va = *(const bf16x8*)&vs[h * 32 + dt * 16 + l15][c2 * 32 + lk];
                    const bf16x8 pa = *(const bf16x8*)&ps[wave][l15][c2 * 32 + lk];
                    o = __builtin_amdgcn_mfma_f32_16x16x32_bf16(va, pa, o, 0, 0, 0);
                }
                u32x2 ow;
                ow.x = pk2(o[0], o[1]);
                ow.y = pk2(o[2], o[3]);
                *(u32x2*)&xt[mt * 16 + l15][h * 32 + dt * 16 + g4] = ow;
            }
        }
    }
    __syncthreads();

    // ---- Phase 4: proj + x-residual -> h into LDS (fp32). Pad rows -> 0. ----
    #pragma unroll
    for (int i = 0; i < 3; ++i) {
        const int t = wave + 8 * i;
        const int mt = t / 6, nt = t - 6 * mt;
        f32x4 acc = {0.f, 0.f, 0.f, 0.f};
        #pragma unroll
        for (int ksp = 0; ksp < 3; ++ksp) {
            const bf16x8 a  = *(const bf16x8*)&xt[mt * 16 + l15][ksp * 32 + lk];
            const bf16x8 bb = *(const bf16x8*)(wproj + (size_t)(nt * 16 + l15) * 96 + ksp * 32 + lk);
            acc = __builtin_amdgcn_mfma_f32_16x16x32_bf16(a, bb, acc, 0, 0, 0);
        }
        const int colf = nt * 16 + l15;
        const float pb = proj_b[colf];
        #pragma unroll
        for (int rr = 0; rr < 4; ++rr) {
            const int n = mt * 16 + g4 + rr;
            if (n < 49) {
                const int p = n / 7, q = n - 7 * p;
                int sr = wi * 7 + p + 3;  if (sr >= 56) sr -= 56;
                int scl = wj * 7 + q + 3; if (scl >= 56) scl -= 56;
                const size_t base = ((size_t)b * 3136 + (size_t)(sr * 56 + scl)) * CDIM + colf;
                hbuf[n][colf] = acc[rr] + pb + x[base];
            } else {
                hbuf[n][colf] = 0.f;
            }
        }
    }
    __syncthreads();

    // ---- Phase 5: LN2 from hbuf -> xs (bf16); 8 threads per row ----
    {
        const int n = tid >> 3, oc = tid & 7;
        float vals[12];
        float s = 0.f, ss2 = 0.f;
        #pragma unroll
        for (int i = 0; i < 3; ++i) {
            const float4 f = *(const float4*)&hbuf[n][oc * 12 + i * 4];
            vals[i*4+0] = f.x; vals[i*4+1] = f.y; vals[i*4+2] = f.z; vals[i*4+3] = f.w;
            s += f.x + f.y + f.z + f.w;
            ss2 += f.x*f.x + f.y*f.y + f.z*f.z + f.w*f.w;
        }
        s += __shfl_xor(s, 1);  ss2 += __shfl_xor(ss2, 1);
        s += __shfl_xor(s, 2);  ss2 += __shfl_xor(ss2, 2);
        s += __shfl_xor(s, 4);  ss2 += __shfl_xor(ss2, 4);
        const float mean = s * (1.f / 96.f);
        const float rstd = rsqrtf(ss2 * (1.f / 96.f) - mean * mean + 1e-5f);
        #pragma unroll
        for (int v4 = 0; v4 < 3; ++v4) {
            const float4 gg = *(const float4*)(ln2_g + oc * 12 + v4 * 4);
            const float4 bb = *(const float4*)(ln2_b + oc * 12 + v4 * 4);
            u32x2 pv;
            pv.x = pk2((vals[v4*4+0]-mean)*rstd*gg.x + bb.x,
                       (vals[v4*4+1]-mean)*rstd*gg.y + bb.y);
            pv.y = pk2((vals[v4*4+2]-mean)*rstd*gg.z + bb.z,
                       (vals[v4*4+3]-mean)*rstd*gg.w + bb.w);
            *(u32x2*)&xs[n][oc * 12 + v4 * 4] = pv;
        }
    }
    __syncthreads();

    // ---- Phase 6: MLP in two hidden chunks of 192; fc2 partials in registers ----
    f32x4 facc[3] = {{0.f,0.f,0.f,0.f},{0.f,0.f,0.f,0.f},{0.f,0.f,0.f,0.f}};
    for (int c = 0; c < 2; ++c) {
        const int hb = c * 192;
        // fc1 chunk + tanh-GELU, swapped GEMM C[hid][tok] -> m1[tok][hid_local]
        #pragma unroll
        for (int i = 0; i < 6; ++i) {
            const int t = wave + 8 * i;              // 0..47
            const int ft = t >> 2, ntt = t & 3;
            f32x4 acc = {0.f, 0.f, 0.f, 0.f};
            #pragma unroll
            for (int ksp = 0; ksp < 3; ++ksp) {
                const bf16x8 a = *(const bf16x8*)(wfc1 + (size_t)(hb + ft * 16 + l15) * 96 + ksp * 32 + lk);
                const bf16x8 bx = *(const bf16x8*)&xs[ntt * 16 + l15][ksp * 32 + lk];
                acc = __builtin_amdgcn_mfma_f32_16x16x32_bf16(a, bx, acc, 0, 0, 0);
            }
            const int f0 = ft * 16 + g4;             // local hidden base 0..188
            const float4 bias = *(const float4*)(fc1_b + hb + f0);
            const float* bp = &bias.x;
            float g[4];
            #pragma unroll
            for (int rr = 0; rr < 4; ++rr) {
                const float u = acc[rr] + bp[rr];
                const float u2 = u * u;
                const float n2y = u * (-1.5957691216f - 0.0713548162f * u2);
                g[rr] = __fdividef(u, 1.f + __expf(n2y));
            }
            u32x2 pw;
            pw.x = pk2(g[0], g[1]);
            pw.y = pk2(g[2], g[3]);
            *(u32x2*)&m1[ntt * 16 + l15][f0] = pw;
        }
        __syncthreads();
        // fc2 partial: C2[cout][tok], K=192 (6 MFMA), acc across chunks
        #pragma unroll
        for (int i = 0; i < 3; ++i) {
            const int t = wave + 8 * i;              // 0..23
            const int ct = t >> 2, tt = t & 3;
            #pragma unroll
            for (int ksp = 0; ksp < 6; ++ksp) {
                const bf16x8 a  = *(const bf16x8*)(wfc2 + (size_t)(ct * 16 + l15) * 384 + hb + ksp * 32 + lk);
                const bf16x8 bm = *(const bf16x8*)&m1[tt * 16 + l15][ksp * 32 + lk];
                facc[i] = __builtin_amdgcn_mfma_f32_16x16x32_bf16(a, bm, facc[i], 0, 0, 0);
            }
        }
        if (c == 0) __syncthreads();                 // protect m1 before chunk-1 fc1
    }

    // ---- Phase 7: epilogue  out = h + fc2 + b2, float4 stores (unshift scatter) ----
    #pragma unroll
    for (int i = 0; i < 3; ++i) {
        const int t = wave + 8 * i;
        const int ct = t >> 2, tt = t & 3;
        const int n = tt * 16 + l15;
        if (n < 49) {
            const int p = n / 7, q = n - 7 * p;
            int sr = wi * 7 + p + 3;  if (sr >= 56) sr -= 56;
            int scl = wj * 7 + q + 3; if (scl >= 56) scl -= 56;
            const int f0 = ct * 16 + g4;
            const float4 hv  = *(const float4*)&hbuf[n][f0];
            const float4 b2v = *(const float4*)(fc2_b + f0);
            float4 o4;
            o4.x = hv.x + facc[i][0] + b2v.x;
            o4.y = hv.y + facc[i][1] + b2v.y;
            o4.z = hv.z + facc[i][2] + b2v.z;
            o4.w = hv.w + facc[i][3] + b2v.w;
            *(float4*)(out + ((size_t)b * 3136 + (size_t)(sr * 56 + scl)) * CDIM + f0) = o4;
        }
    }
}

extern "C" void kernel_launch(void* const* d_in, const int* in_sizes, int n_in,
                              void* d_out, int out_size, void* d_ws, size_t ws_size,
                              hipStream_t stream) {
    (void)n_in; (void)out_size; (void)ws_size;
    const float* x        = (const float*)d_in[0];
    const float* attn_msk = (const float*)d_in[1];
    const float* ln1_g    = (const float*)d_in[2];
    const float* ln1_b    = (const float*)d_in[3];
    const float* qkv_w    = (const float*)d_in[4];
    const float* qkv_b    = (const float*)d_in[5];
    const float* rel_tab  = (const float*)d_in[6];
    const int*   rel_idx  = (const int*)d_in[7];
    const float* proj_w   = (const float*)d_in[8];
    const float* proj_b   = (const float*)d_in[9];
    const float* ln2_g    = (const float*)d_in[10];
    const float* ln2_b    = (const float*)d_in[11];
    const float* fc1_w    = (const float*)d_in[12];
    const float* fc1_b    = (const float*)d_in[13];
    const float* fc2_w    = (const float*)d_in[14];
    const float* fc2_b    = (const float*)d_in[15];
    float* out = (float*)d_out;
    unsigned short* wsb = (unsigned short*)d_ws;
    unsigned short* bmf = wsb + 110592;

    const int B = in_sizes[0] / (3136 * 96);   // 64

    conv_w_kernel<<<(110592 + 255) / 256, 256, 0, stream>>>(qkv_w, proj_w, fc1_w, fc2_w, wsb);
    build_bmfrag_kernel<<<196608 / 256, 256, 0, stream>>>(attn_msk, rel_tab, rel_idx, bmf);

    swin_fused<<<B * 64, 512, 0, stream>>>(
        x, ln1_g, ln1_b, qkv_b, proj_b, ln2_g, ln2_b, fc1_b, fc2_b,
        wsb, wsb + 27648, wsb + 36864, wsb + 73728, bmf, out);
}

// Round 7
// 331.201 us; speedup vs baseline: 1.0415x; 1.0415x over previous
//
#include <hip/hip_runtime.h>
#include <math.h>

// Swin block, single fused bf16-MFMA kernel, register-exchanged P, cvt_pk packing.
// B=64, H=W=56, C=96, WS=7, SS=3, NH=3, HD=32, N=49 (padded 64), nW=64.

#define CDIM 96
#define SCALE_QK 0.17677669529663687f  // 32^-0.5
#define NW 8

typedef __attribute__((ext_vector_type(8))) short bf16x8;
typedef __attribute__((ext_vector_type(4))) float f32x4;
typedef __attribute__((ext_vector_type(2))) unsigned int u32x2;
typedef __attribute__((ext_vector_type(4))) unsigned int u32x4;

__device__ inline unsigned short f2b(float f) {
    union { float f; unsigned u; } v; v.f = f;
    unsigned r = v.u + 0x7FFF + ((v.u >> 16) & 1);   // RNE
    return (unsigned short)(r >> 16);
}
__device__ inline unsigned pkcvt(float a, float b) {   // low16=bf16(a), high16=bf16(b)
    unsigned d;
    asm("v_cvt_pk_bf16_f32 %0, %1, %2" : "=v"(d) : "v"(a), "v"(b));
    return d;
}
__device__ inline float bitsf(unsigned u) {
    union { unsigned u; float f; } v; v.u = u; return v.f;
}
__device__ inline bf16x8 mk8(unsigned d0, unsigned d1, unsigned d2, unsigned d3) {
    union { u32x4 u; bf16x8 h; } v;
    v.u = (u32x4){d0, d1, d2, d3};
    return v.h;
}

// ---------------- Kernel 0a: weights fp32 -> bf16 ----------------
// ws shorts: qkv_w [288*96] @0, proj_w @27648, fc1_w @36864, fc2_w @73728 (end 110592),
// bm_frag bf16 @110592.
__global__ __launch_bounds__(256) void conv_w_kernel(
    const float* __restrict__ qkv_w, const float* __restrict__ proj_w,
    const float* __restrict__ fc1_w, const float* __restrict__ fc2_w,
    unsigned short* __restrict__ ws)
{
    const int i = blockIdx.x * 256 + threadIdx.x;
    if (i < 27648)       ws[i] = f2b(qkv_w[i]);
    else if (i < 36864)  ws[i] = f2b(proj_w[i - 27648]);
    else if (i < 73728)  ws[i] = f2b(fc1_w[i - 36864]);
    else if (i < 110592) ws[i] = f2b(fc2_w[i - 73728]);
}

// ---------------- Kernel 0b: bias+mask in MFMA C-fragment layout, bf16 ----------------
__global__ __launch_bounds__(256) void build_bmfrag_kernel(
    const float* __restrict__ attn_mask, const float* __restrict__ rel_bias_table,
    const int* __restrict__ rel_index, unsigned short* __restrict__ bmf)
{
    const int i = blockIdx.x * 256 + threadIdx.x;   // 196608 total
    const int lane = i & 63;
    const int mt = (i >> 6) & 3;
    const int kt = (i >> 8) & 3;
    const int t3 = i >> 10;                          // widx*3 + h
    const int h = t3 % 3, widx = t3 / 3;
    const int q = mt * 16 + (lane & 15);
    const int kb = kt * 16 + (lane >> 4) * 4;
    float vv[4];
    #pragma unroll
    for (int rr = 0; rr < 4; ++rr) {
        const int k = kb + rr;
        float val = -1.0e30f;
        if (q < 49 && k < 49) {
            const int idx = q * 49 + k;
            val = rel_bias_table[rel_index[idx] * 3 + h] + attn_mask[widx * 2401 + idx];
        }
        vv[rr] = val;
    }
    u32x2 pw;
    pw.x = (unsigned)f2b(vv[0]) | ((unsigned)f2b(vv[1]) << 16);
    pw.y = (unsigned)f2b(vv[2]) | ((unsigned)f2b(vv[3]) << 16);
    *(u32x2*)(bmf + (size_t)i * 4) = pw;
}

// ---------------- Fused kernel ----------------
// LDS (53760 B): xt [64][104]u16 @0 | qs [64][104] @13312 | kss [64][104] @26624 |
//                vs [96][72] @39936.  Aliases after attn: m1 [64][104]u16 @13312,
//                hbuf [64][101]f32 @26624 (ends 52480).
__global__ __launch_bounds__(512, 6) void swin_fused(
    const float* __restrict__ x,
    const float* __restrict__ ln1_g, const float* __restrict__ ln1_b,
    const float* __restrict__ qkv_b, const float* __restrict__ proj_b,
    const float* __restrict__ ln2_g, const float* __restrict__ ln2_b,
    const float* __restrict__ fc1_b, const float* __restrict__ fc2_b,
    const unsigned short* __restrict__ wqkv,   // [288][96] bf16
    const unsigned short* __restrict__ wproj,  // [96][96] bf16
    const unsigned short* __restrict__ wfc1,   // [384][96] bf16
    const unsigned short* __restrict__ wfc2,   // [96][384] bf16
    const unsigned short* __restrict__ bmfrag,
    float* __restrict__ out)
{
    __shared__ __align__(16) unsigned char smem[53760];
    unsigned short (*xt)[104]  = (unsigned short(*)[104])(smem);
    unsigned short (*qs)[104]  = (unsigned short(*)[104])(smem + 13312);
    unsigned short (*kss)[104] = (unsigned short(*)[104])(smem + 26624);
    unsigned short (*vs)[72]   = (unsigned short(*)[72])(smem + 39936);
    unsigned short (*m1)[104]  = (unsigned short(*)[104])(smem + 13312);
    float          (*hbuf)[101]= (float(*)[101])(smem + 26624);
    unsigned short (*xs)[104]  = xt;

    const int w = blockIdx.x, b = w >> 6, widx = w & 63;
    const int wi = widx >> 3, wj = widx & 7;
    const int tid = threadIdx.x, wave = tid >> 6, lane = tid & 63;
    const int l15 = lane & 15, lk = (lane >> 4) * 8, g4 = (lane >> 4) * 4;

    // ---- Phase 1: LN1 + shifted gather (roll -3,-3); 8 threads per row ----
    {
        const int n = tid >> 3, oc = tid & 7;
        if (n < 49) {
            const int p = n / 7, qq = n - 7 * p;
            int sr = wi * 7 + p + 3;   if (sr >= 56) sr -= 56;
            int scl = wj * 7 + qq + 3; if (scl >= 56) scl -= 56;
            const float* xr = x + ((size_t)b * 3136 + (size_t)(sr * 56 + scl)) * CDIM + oc * 12;
            float vals[12];
            float s = 0.f, ss2 = 0.f;
            #pragma unroll
            for (int i = 0; i < 3; ++i) {
                const float4 f = *(const float4*)(xr + i * 4);
                vals[i*4+0] = f.x; vals[i*4+1] = f.y; vals[i*4+2] = f.z; vals[i*4+3] = f.w;
                s += f.x + f.y + f.z + f.w;
                ss2 += f.x*f.x + f.y*f.y + f.z*f.z + f.w*f.w;
            }
            s += __shfl_xor(s, 1);  ss2 += __shfl_xor(ss2, 1);
            s += __shfl_xor(s, 2);  ss2 += __shfl_xor(ss2, 2);
            s += __shfl_xor(s, 4);  ss2 += __shfl_xor(ss2, 4);
            const float mean = s * (1.f / 96.f);
            const float rstd = rsqrtf(ss2 * (1.f / 96.f) - mean * mean + 1e-5f);
            #pragma unroll
            for (int v4 = 0; v4 < 3; ++v4) {
                const float4 gg = *(const float4*)(ln1_g + oc * 12 + v4 * 4);
                const float4 bb = *(const float4*)(ln1_b + oc * 12 + v4 * 4);
                u32x2 pv;
                pv.x = pkcvt((vals[v4*4+0]-mean)*rstd*gg.x + bb.x,
                             (vals[v4*4+1]-mean)*rstd*gg.y + bb.y);
                pv.y = pkcvt((vals[v4*4+2]-mean)*rstd*gg.z + bb.z,
                             (vals[v4*4+3]-mean)*rstd*gg.w + bb.w);
                *(u32x2*)&xt[n][oc * 12 + v4 * 4] = pv;
            }
        } else {
            const u32x2 z = {0u, 0u};
            #pragma unroll
            for (int v4 = 0; v4 < 3; ++v4) *(u32x2*)&xt[n][oc * 12 + v4 * 4] = z;
        }
    }
    __syncthreads();

    // ---- Phase 2: qkv projection ----
    #pragma unroll
    for (int i = 0; i < 9; ++i) {
        const int t = wave + 8 * i;
        if (t < 48) {
            const int qt = t >> 2, ntt = t & 3;
            f32x4 acc = {0.f, 0.f, 0.f, 0.f};
            #pragma unroll
            for (int ksp = 0; ksp < 3; ++ksp) {
                const bf16x8 a = *(const bf16x8*)(wqkv + (size_t)(qt * 16 + l15) * 96 + ksp * 32 + lk);
                const bf16x8 bx = *(const bf16x8*)&xt[ntt * 16 + l15][ksp * 32 + lk];
                acc = __builtin_amdgcn_mfma_f32_16x16x32_bf16(a, bx, acc, 0, 0, 0);
            }
            const int f0 = qt * 16 + g4;
            const float4 bias = *(const float4*)(qkv_b + f0);
            const int tok = ntt * 16 + l15;
            u32x2 pw;
            if (qt < 6) {
                pw.x = pkcvt((acc[0] + bias.x) * SCALE_QK, (acc[1] + bias.y) * SCALE_QK);
                pw.y = pkcvt((acc[2] + bias.z) * SCALE_QK, (acc[3] + bias.w) * SCALE_QK);
                *(u32x2*)&qs[tok][f0] = pw;
            } else {
                pw.x = pkcvt(acc[0] + bias.x, acc[1] + bias.y);
                pw.y = pkcvt(acc[2] + bias.z, acc[3] + bias.w);
                *(u32x2*)&kss[tok][f0 - 96] = pw;
            }
        } else {
            const int u = t - 48, mtt = u / 6, vt = u - 6 * mtt;
            f32x4 acc = {0.f, 0.f, 0.f, 0.f};
            #pragma unroll
            for (int ksp = 0; ksp < 3; ++ksp) {
                const bf16x8 a = *(const bf16x8*)&xt[mtt * 16 + l15][ksp * 32 + lk];
                const bf16x8 bw = *(const bf16x8*)(wqkv + (size_t)(192 + vt * 16 + l15) * 96 + ksp * 32 + lk);
                acc = __builtin_amdgcn_mfma_f32_16x16x32_bf16(a, bw, acc, 0, 0, 0);
            }
            const float bias = qkv_b[192 + vt * 16 + l15];
            u32x2 pw;
            pw.x = pkcvt(acc[0] + bias, acc[1] + bias);
            pw.y = pkcvt(acc[2] + bias, acc[3] + bias);
            *(u32x2*)&vs[vt * 16 + l15][mtt * 16 + g4] = pw;
        }
    }
    __syncthreads();

    // ---- Phase 3: swapped QK^T + register softmax + in-register P exchange + PV ----
    #pragma unroll
    for (int it = 0; it < 2; ++it) {
        const int ui = wave + 8 * it;
        if (ui < 12) {
            const int h = ui >> 2, mt = ui & 3;
            const bf16x8 bq = *(const bf16x8*)&qs[mt * 16 + l15][h * 32 + lk];
            const unsigned short* bmb = bmfrag + (size_t)(widx * 3 + h) * 4096 + mt * 256;
            f32x4 s[4];
            #pragma unroll
            for (int kt = 0; kt < 4; ++kt) {
                const bf16x8 ak = *(const bf16x8*)&kss[kt * 16 + l15][h * 32 + lk];
                const u32x2 cw = *(const u32x2*)(bmb + kt * 1024 + lane * 4);
                f32x4 c;
                c[0] = bitsf(cw.x << 16); c[1] = bitsf(cw.x & 0xffff0000u);
                c[2] = bitsf(cw.y << 16); c[3] = bitsf(cw.y & 0xffff0000u);
                s[kt] = __builtin_amdgcn_mfma_f32_16x16x32_bf16(ak, bq, c, 0, 0, 0);
            }
            float mx = s[0][0];
            #pragma unroll
            for (int kt = 0; kt < 4; ++kt)
                #pragma unroll
                for (int rr = 0; rr < 4; ++rr) mx = fmaxf(mx, s[kt][rr]);
            mx = fmaxf(mx, __shfl_xor(mx, 16));
            mx = fmaxf(mx, __shfl_xor(mx, 32));
            float sum = 0.f;
            #pragma unroll
            for (int kt = 0; kt < 4; ++kt)
                #pragma unroll
                for (int rr = 0; rr < 4; ++rr) {
                    const float e = __expf(s[kt][rr] - mx);
                    s[kt][rr] = e; sum += e;
                }
            sum += __shfl_xor(sum, 16);
            sum += __shfl_xor(sum, 32);
            const float inv = __fdividef(1.0f, sum);
            // pack P pairs: pk[kt][i] = bf16x2(P[kt*16+g*4+2i][q], P[..+2i+1][q])
            unsigned pk00 = pkcvt(s[0][0], s[0][1]), pk01 = pkcvt(s[0][2], s[0][3]);
            unsigned pk10 = pkcvt(s[1][0], s[1][1]), pk11 = pkcvt(s[1][2], s[1][3]);
            unsigned pk20 = pkcvt(s[2][0], s[2][1]), pk21 = pkcvt(s[2][2], s[2][3]);
            unsigned pk30 = pkcvt(s[3][0], s[3][1]), pk31 = pkcvt(s[3][2], s[3][3]);
            // exchange: consumer (g,q) B-frag chunk c2 dword j holds P[c2*32+g*8+2j..+1][q]
            // = pk[2c2+(g>>1)][j&1] of lane (2(g&1)+(j>>1))*16 + q
            const int srcA = ((lane >> 4) & 1) * 32 + l15;
            const int srcB = srcA + 16;
            const bool hi = (lane & 32) != 0;
            unsigned a0, a1, a2, a3, b0, b1, b2, b3;
            a0 = __shfl(pk00, srcA); a1 = __shfl(pk01, srcA);
            a2 = __shfl(pk10, srcA); a3 = __shfl(pk11, srcA);
            b0 = __shfl(pk00, srcB); b1 = __shfl(pk01, srcB);
            b2 = __shfl(pk10, srcB); b3 = __shfl(pk11, srcB);
            const bf16x8 pb0 = mk8(hi ? a2 : a0, hi ? a3 : a1, hi ? b2 : b0, hi ? b3 : b1);
            a0 = __shfl(pk20, srcA); a1 = __shfl(pk21, srcA);
            a2 = __shfl(pk30, srcA); a3 = __shfl(pk31, srcA);
            b0 = __shfl(pk20, srcB); b1 = __shfl(pk21, srcB);
            b2 = __shfl(pk30, srcB); b3 = __shfl(pk31, srcB);
            const bf16x8 pb1 = mk8(hi ? a2 : a0, hi ? a3 : a1, hi ? b2 : b0, hi ? b3 : b1);
            // PV swapped: O'[d][q]; normalize after
            f32x4 o0 = {0.f,0.f,0.f,0.f}, o1 = {0.f,0.f,0.f,0.f};
            {
                const bf16x8 v00 = *(const bf16x8*)&vs[h * 32 + l15][lk];
                const bf16x8 v01 = *(const bf16x8*)&vs[h * 32 + l15][32 + lk];
                const bf16x8 v10 = *(const bf16x8*)&vs[h * 32 + 16 + l15][lk];
                const bf16x8 v11 = *(const bf16x8*)&vs[h * 32 + 16 + l15][32 + lk];
                o0 = __builtin_amdgcn_mfma_f32_16x16x32_bf16(v00, pb0, o0, 0, 0, 0);
                o0 = __builtin_amdgcn_mfma_f32_16x16x32_bf16(v01, pb1, o0, 0, 0, 0);
                o1 = __builtin_amdgcn_mfma_f32_16x16x32_bf16(v10, pb0, o1, 0, 0, 0);
                o1 = __builtin_amdgcn_mfma_f32_16x16x32_bf16(v11, pb1, o1, 0, 0, 0);
            }
            u32x2 ow;
            ow.x = pkcvt(o0[0] * inv, o0[1] * inv);
            ow.y = pkcvt(o0[2] * inv, o0[3] * inv);
            *(u32x2*)&xt[mt * 16 + l15][h * 32 + g4] = ow;
            ow.x = pkcvt(o1[0] * inv, o1[1] * inv);
            ow.y = pkcvt(o1[2] * inv, o1[3] * inv);
            *(u32x2*)&xt[mt * 16 + l15][h * 32 + 16 + g4] = ow;
        }
    }
    __syncthreads();

    // ---- Phase 4: proj + x-residual -> hbuf (fp32). Pad rows -> 0. ----
    #pragma unroll
    for (int i = 0; i < 3; ++i) {
        const int t = wave + 8 * i;
        const int mt = t / 6, nt = t - 6 * mt;
        f32x4 acc = {0.f, 0.f, 0.f, 0.f};
        #pragma unroll
        for (int ksp = 0; ksp < 3; ++ksp) {
            const bf16x8 a  = *(const bf16x8*)&xt[mt * 16 + l15][ksp * 32 + lk];
            const bf16x8 bb = *(const bf16x8*)(wproj + (size_t)(nt * 16 + l15) * 96 + ksp * 32 + lk);
            acc = __builtin_amdgcn_mfma_f32_16x16x32_bf16(a, bb, acc, 0, 0, 0);
        }
        const int colf = nt * 16 + l15;
        const float pb = proj_b[colf];
        #pragma unroll
        for (int rr = 0; rr < 4; ++rr) {
            const int n = mt * 16 + g4 + rr;
            if (n < 49) {
                const int p = n / 7, q = n - 7 * p;
                int sr = wi * 7 + p + 3;  if (sr >= 56) sr -= 56;
                int scl = wj * 7 + q + 3; if (scl >= 56) scl -= 56;
                const size_t base = ((size_t)b * 3136 + (size_t)(sr * 56 + scl)) * CDIM + colf;
                hbuf[n][colf] = acc[rr] + pb + x[base];
            } else {
                hbuf[n][colf] = 0.f;
            }
        }
    }
    __syncthreads();

    // ---- Phase 5: LN2 hbuf -> xs (bf16) ----
    {
        const int n = tid >> 3, oc = tid & 7;
        float vals[12];
        float s = 0.f, ss2 = 0.f;
        #pragma unroll
        for (int i = 0; i < 3; ++i) {
            const float4 f = *(const float4*)&hbuf[n][oc * 12 + i * 4];
            vals[i*4+0] = f.x; vals[i*4+1] = f.y; vals[i*4+2] = f.z; vals[i*4+3] = f.w;
            s += f.x + f.y + f.z + f.w;
            ss2 += f.x*f.x + f.y*f.y + f.z*f.z + f.w*f.w;
        }
        s += __shfl_xor(s, 1);  ss2 += __shfl_xor(ss2, 1);
        s += __shfl_xor(s, 2);  ss2 += __shfl_xor(ss2, 2);
        s += __shfl_xor(s, 4);  ss2 += __shfl_xor(ss2, 4);
        const float mean = s * (1.f / 96.f);
        const float rstd = rsqrtf(ss2 * (1.f / 96.f) - mean * mean + 1e-5f);
        #pragma unroll
        for (int v4 = 0; v4 < 3; ++v4) {
            const float4 gg = *(const float4*)(ln2_g + oc * 12 + v4 * 4);
            const float4 bb = *(const float4*)(ln2_b + oc * 12 + v4 * 4);
            u32x2 pv;
            pv.x = pkcvt((vals[v4*4+0]-mean)*rstd*gg.x + bb.x,
                         (vals[v4*4+1]-mean)*rstd*gg.y + bb.y);
            pv.y = pkcvt((vals[v4*4+2]-mean)*rstd*gg.z + bb.z,
                         (vals[v4*4+3]-mean)*rstd*gg.w + bb.w);
            *(u32x2*)&xs[n][oc * 12 + v4 * 4] = pv;
        }
    }
    __syncthreads();

    // ---- Phase 6: MLP, 4 hidden chunks of 96; fc2 partials in registers ----
    f32x4 facc[3] = {{0.f,0.f,0.f,0.f},{0.f,0.f,0.f,0.f},{0.f,0.f,0.f,0.f}};
    #pragma unroll
    for (int c = 0; c < 4; ++c) {
        const int hb = c * 96;
        #pragma unroll
        for (int i = 0; i < 3; ++i) {
            const int t = wave + 8 * i;              // 0..23
            const int ft = t >> 2, ntt = t & 3;
            f32x4 acc = {0.f, 0.f, 0.f, 0.f};
            #pragma unroll
            for (int ksp = 0; ksp < 3; ++ksp) {
                const bf16x8 a = *(const bf16x8*)(wfc1 + (size_t)(hb + ft * 16 + l15) * 96 + ksp * 32 + lk);
                const bf16x8 bx = *(const bf16x8*)&xs[ntt * 16 + l15][ksp * 32 + lk];
                acc = __builtin_amdgcn_mfma_f32_16x16x32_bf16(a, bx, acc, 0, 0, 0);
            }
            const int f0 = ft * 16 + g4;
            const float4 bias = *(const float4*)(fc1_b + hb + f0);
            const float* bp = &bias.x;
            float g[4];
            #pragma unroll
            for (int rr = 0; rr < 4; ++rr) {
                const float u = acc[rr] + bp[rr];
                const float u2 = u * u;
                const float n2y = u * (-1.5957691216f - 0.0713548162f * u2);
                g[rr] = __fdividef(u, 1.f + __expf(n2y));
            }
            u32x2 pw;
            pw.x = pkcvt(g[0], g[1]);
            pw.y = pkcvt(g[2], g[3]);
            *(u32x2*)&m1[ntt * 16 + l15][f0] = pw;
        }
        __syncthreads();
        #pragma unroll
        for (int i = 0; i < 3; ++i) {
            const int t = wave + 8 * i;              // 0..23
            const int ct = t >> 2, tt = t & 3;
            #pragma unroll
            for (int ksp = 0; ksp < 3; ++ksp) {
                const bf16x8 a  = *(const bf16x8*)(wfc2 + (size_t)(ct * 16 + l15) * 384 + hb + ksp * 32 + lk);
                const bf16x8 bm = *(const bf16x8*)&m1[tt * 16 + l15][ksp * 32 + lk];
                facc[i] = __builtin_amdgcn_mfma_f32_16x16x32_bf16(a, bm, facc[i], 0, 0, 0);
            }
        }
        if (c < 3) __syncthreads();
    }

    // ---- Phase 7: out = h + fc2 + b2, float4 stores (unshift scatter) ----
    #pragma unroll
    for (int i = 0; i < 3; ++i) {
        const int t = wave + 8 * i;
        const int ct = t >> 2, tt = t & 3;
        const int n = tt * 16 + l15;
        if (n < 49) {
            const int p = n / 7, q = n - 7 * p;
            int sr = wi * 7 + p + 3;  if (sr >= 56) sr -= 56;
            int scl = wj * 7 + q + 3; if (scl >= 56) scl -= 56;
            const int f0 = ct * 16 + g4;
            const float4 hv  = *(const float4*)&hbuf[n][f0];
            const float4 b2v = *(const float4*)(fc2_b + f0);
            float4 o4;
            o4.x = hv.x + facc[i][0] + b2v.x;
            o4.y = hv.y + facc[i][1] + b2v.y;
            o4.z = hv.z + facc[i][2] + b2v.z;
            o4.w = hv.w + facc[i][3] + b2v.w;
            *(float4*)(out + ((size_t)b * 3136 + (size_t)(sr * 56 + scl)) * CDIM + f0) = o4;
        }
    }
}

extern "C" void kernel_launch(void* const* d_in, const int* in_sizes, int n_in,
                              void* d_out, int out_size, void* d_ws, size_t ws_size,
                              hipStream_t stream) {
    (void)n_in; (void)out_size; (void)ws_size;
    const float* x        = (const float*)d_in[0];
    const float* attn_msk = (const float*)d_in[1];
    const float* ln1_g    = (const float*)d_in[2];
    const float* ln1_b    = (const float*)d_in[3];
    const float* qkv_w    = (const float*)d_in[4];
    const float* qkv_b    = (const float*)d_in[5];
    const float* rel_tab  = (const float*)d_in[6];
    const int*   rel_idx  = (const int*)d_in[7];
    const float* proj_w   = (const float*)d_in[8];
    const float* proj_b   = (const float*)d_in[9];
    const float* ln2_g    = (const float*)d_in[10];
    const float* ln2_b    = (const float*)d_in[11];
    const float* fc1_w    = (const float*)d_in[12];
    const float* fc1_b    = (const float*)d_in[13];
    const float* fc2_w    = (const float*)d_in[14];
    const float* fc2_b    = (const float*)d_in[15];
    float* out = (float*)d_out;
    unsigned short* wsb = (unsigned short*)d_ws;
    unsigned short* bmf = wsb + 110592;

    const int B = in_sizes[0] / (3136 * 96);   // 64

    conv_w_kernel<<<(110592 + 255) / 256, 256, 0, stream>>>(qkv_w, proj_w, fc1_w, fc2_w, wsb);
    build_bmfrag_kernel<<<196608 / 256, 256, 0, stream>>>(attn_msk, rel_tab, rel_idx, bmf);

    swin_fused<<<B * 64, 512, 0, stream>>>(
        x, ln1_g, ln1_b, qkv_b, proj_b, ln2_g, ln2_b, fc1_b, fc2_b,
        wsb, wsb + 27648, wsb + 36864, wsb + 73728, bmf, out);
}